// Round 1
// baseline (1298.969 us; speedup 1.0000x reference)
//
#include <hip/hip_runtime.h>
#include <hip/hip_fp16.h>

#define NN 100   // nodes
#define HH 32    // hidden
#define BB 8192  // batch
#define DD 32    // dags

// ---- prep 1: W1 (N,H,N+1) -> W1T (N, N+1, H) so per-parent weights are contiguous
__global__ void prep_w1t(const float* __restrict__ W1, float* __restrict__ W1T) {
  int idx = blockIdx.x * 256 + threadIdx.x;
  const int total = NN * (NN + 1) * HH;
  if (idx >= total) return;
  int j = idx & (HH - 1);          // hidden index
  int rest = idx >> 5;
  int i = rest % (NN + 1);         // input index
  int node = rest / (NN + 1);
  W1T[idx] = W1[((size_t)node * HH + j) * (NN + 1) + i];
}

// ---- prep 2: x (B,N) -> xT (N,B) for coalesced per-step loads
__global__ void prep_xt(const float* __restrict__ x, float* __restrict__ xT) {
  int idx = blockIdx.x * 256 + threadIdx.x;
  if (idx >= BB * NN) return;
  int b = idx & (BB - 1);
  int n = idx >> 13;               // BB = 2^13
  xT[idx] = x[(size_t)b * NN + n];
}

// ---- prep 3: pack adjacency column A[d, :, node] into 4 x u32 bitmask
__global__ void prep_mask(const float* __restrict__ A, unsigned* __restrict__ mbits) {
  int t = blockIdx.x * 256 + threadIdx.x;
  if (t >= DD * NN) return;
  int d = t / NN, node = t - d * NN;
  unsigned m0 = 0, m1 = 0, m2 = 0, m3 = 0;
  for (int i = 0; i < NN; i++) {
    unsigned bit = (A[((size_t)d * NN + i) * NN + node] != 0.f) ? 1u : 0u;
    if (i < 32)       m0 |= bit << (i);
    else if (i < 64)  m1 |= bit << (i - 32);
    else if (i < 96)  m2 |= bit << (i - 64);
    else              m3 |= bit << (i - 96);
  }
  mbits[t * 4 + 0] = m0;
  mbits[t * 4 + 1] = m1;
  mbits[t * 4 + 2] = m2;
  mbits[t * 4 + 3] = m3;
}

// ---- main: one thread per batch row, one block-column per dag
__global__ __launch_bounds__(256, 4) void dag_main(
    const float* __restrict__ xT,      // [N][B]
    const int* __restrict__ order,     // [D][N]
    const int* __restrict__ do_idx_p,  // [1]
    const float* __restrict__ W1T,     // [N][N+1][H]
    const float* __restrict__ b1,      // [N][H]
    const float* __restrict__ W2,      // [N][H]
    const float* __restrict__ b2,      // [N]
    const unsigned* __restrict__ mbits,// [D][N][4]
    float* __restrict__ out)           // [D][B][N]
{
  const int d = blockIdx.y;
  const int tid = threadIdx.x;
  const int b0 = blockIdx.x * 256;
  const int brow = b0 + tid;
  const int do_idx = do_idx_p[0];

  // node outputs, fp16-packed in VGPRs (statically indexed everywhere)
  unsigned outs_u[NN / 2];
#pragma unroll
  for (int i = 0; i < NN / 2; i++) outs_u[i] = 0u;

#pragma unroll 1
  for (int step = 0; step < NN; step++) {
    const int node = order[d * NN + step];        // uniform -> SGPR
    const float xv = xT[(size_t)node * BB + brow]; // coalesced
    float val;
    if (node != do_idx) {
      const float* __restrict__ w1n = W1T + (size_t)node * (NN + 1) * HH;
      const float* __restrict__ b1n = b1 + node * HH;
      float acc[HH];
#pragma unroll
      for (int j = 0; j < HH; j++) acc[j] = fmaf(w1n[NN * HH + j], xv, b1n[j]);

      const unsigned* __restrict__ mbp = mbits + ((size_t)d * NN + node) * 4;
      const unsigned mm0 = mbp[0], mm1 = mbp[1], mm2 = mbp[2], mm3 = mbp[3];
#pragma unroll
      for (int i = 0; i < NN; i++) {
        const unsigned mw = (i < 32) ? mm0 : (i < 64) ? mm1 : (i < 96) ? mm2 : mm3;
        if ((mw >> (i & 31)) & 1u) {            // wave-uniform -> scalar branch
          const unsigned u = outs_u[i >> 1];
          const unsigned short us =
              (unsigned short)((i & 1) ? (u >> 16) : (u & 0xFFFFu));
          const float v = __half2float(__ushort_as_half(us));
          const float* __restrict__ w = w1n + i * HH;
#pragma unroll
          for (int j = 0; j < HH; j++) acc[j] = fmaf(w[j], v, acc[j]);
        }
      }
      float o = b2[node];
      const float* __restrict__ w2n = W2 + node * HH;
#pragma unroll
      for (int j = 0; j < HH; j++) {
        float h = acc[j];
        h = fmaxf(h, 0.01f * h);               // leaky_relu, slope 0.01
        o = fmaf(w2n[j], h, o);
      }
      val = o;
    } else {
      val = xv;
    }
    // outs[node] = val  (runtime-uniform index -> unrolled uniform selects)
    const unsigned hv = (unsigned)__half_as_ushort(__float2half(val));
    const int slot = node >> 1;
    const unsigned odd = (unsigned)(node & 1);
    const unsigned keepmask = odd ? 0x0000FFFFu : 0xFFFF0000u;
    const unsigned insbits = odd ? (hv << 16) : hv;
#pragma unroll
    for (int i = 0; i < NN / 2; i++) {
      if (i == slot) outs_u[i] = (outs_u[i] & keepmask) | insbits;
    }
  }

  // coalesced output write via 32-row LDS transpose chunks
  __shared__ float lds[32][101];
#pragma unroll 1
  for (int c = 0; c < 8; c++) {
    __syncthreads();
    const int lr = tid - c * 32;
    if (lr >= 0 && lr < 32) {
#pragma unroll
      for (int i = 0; i < NN / 2; i++) {
        const unsigned u = outs_u[i];
        lds[lr][2 * i]     = __half2float(__ushort_as_half((unsigned short)(u & 0xFFFFu)));
        lds[lr][2 * i + 1] = __half2float(__ushort_as_half((unsigned short)(u >> 16)));
      }
    }
    __syncthreads();
    for (int idx = tid; idx < 32 * NN; idx += 256) {
      const int r = idx / NN;
      const int col = idx - r * NN;
      out[((size_t)d * BB + b0 + c * 32 + r) * NN + col] = lds[r][col];
    }
  }
}

extern "C" void kernel_launch(void* const* d_in, const int* in_sizes, int n_in,
                              void* d_out, int out_size, void* d_ws, size_t ws_size,
                              hipStream_t stream) {
  const float* x     = (const float*)d_in[0];
  const float* A     = (const float*)d_in[1];
  const int* order   = (const int*)d_in[2];
  const int* do_idx  = (const int*)d_in[3];
  const float* W1    = (const float*)d_in[4];
  const float* b1    = (const float*)d_in[5];
  const float* W2    = (const float*)d_in[6];
  const float* b2    = (const float*)d_in[7];
  float* out = (float*)d_out;

  char* ws = (char*)d_ws;
  float* W1T     = (float*)ws;                              // 323200 f = 1,292,800 B
  float* xT      = (float*)(ws + 1292800);                  // 819200 f = 3,276,800 B
  unsigned* mbts = (unsigned*)(ws + 1292800 + 3276800);     // 12800 u32 = 51,200 B

  hipLaunchKernelGGL(prep_w1t, dim3((NN * (NN + 1) * HH + 255) / 256), dim3(256), 0, stream,
                     W1, W1T);
  hipLaunchKernelGGL(prep_xt, dim3((BB * NN) / 256), dim3(256), 0, stream, x, xT);
  hipLaunchKernelGGL(prep_mask, dim3((DD * NN + 255) / 256), dim3(256), 0, stream, A, mbts);
  hipLaunchKernelGGL(dag_main, dim3(BB / 256, DD), dim3(256), 0, stream,
                     xT, order, do_idx, W1T, b1, W2, b2, mbts, out);
}

// Round 2
// 555.394 us; speedup vs baseline: 2.3388x; 2.3388x over previous
//
#include <hip/hip_runtime.h>
#include <hip/hip_fp16.h>

#define NN 100   // nodes
#define HH 32    // hidden
#define BB 8192  // batch
#define DD 32    // dags
#define KP 128   // padded K (100 outs + 1 x + 1 ones + pad)

typedef _Float16 f16x8 __attribute__((ext_vector_type(8)));
typedef float f32x4 __attribute__((ext_vector_type(4)));
typedef unsigned short ushort_t;

union FU { uint4 u; f16x8 h; };

// ---- prep 1: x (B,N) -> xT (N,B)
__global__ void prep_xt(const float* __restrict__ x, float* __restrict__ xT) {
  int idx = blockIdx.x * 256 + threadIdx.x;
  if (idx >= BB * NN) return;
  int b = idx & (BB - 1);
  int n = idx >> 13;
  xT[idx] = x[(size_t)b * NN + n];
}

// ---- prep 2: W1 (N,H,N+1) + b1 -> W1A fp16 [N][H][KP] (K-major, ones-row=b1, pad=0)
__global__ void prep_w1a(const float* __restrict__ W1, const float* __restrict__ b1,
                         ushort_t* __restrict__ W1A) {
  int idx = blockIdx.x * 256 + threadIdx.x;   // 100*32*128 = 409600 = 1600*256
  int node = idx >> 12;
  int rem = idx & 4095;
  int j = rem >> 7;
  int k = rem & 127;
  float v;
  if (k <= NN) v = W1[((size_t)node * HH + j) * (NN + 1) + k];
  else if (k == NN + 1) v = b1[node * HH + j];
  else v = 0.f;
  W1A[idx] = __half_as_ushort(__float2half_rn(v));
}

// ---- prep 3: mask expansion: mexp[d][node][k] = 0xFFFF if input k active else 0
__global__ void prep_mexp(const float* __restrict__ A, ushort_t* __restrict__ mexp) {
  int idx = blockIdx.x * 256 + threadIdx.x;   // 32*100*128 = 409600
  int d = idx / 12800;
  int rem = idx - d * 12800;
  int node = rem >> 7;
  int k = rem & 127;
  ushort_t v;
  if (k < NN) v = (A[((size_t)d * NN + k) * NN + node] != 0.f) ? 0xFFFFu : 0u;
  else if (k <= NN + 1) v = 0xFFFFu;  // x row (100) and ones row (101) always on
  else v = 0u;
  mexp[idx] = v;
}

// ---- main: 4 independent waves per block, 64 batch rows per wave, outs in VGPRs
__global__ __launch_bounds__(256, 3) void dag_mfma(
    const float* __restrict__ xT,      // [N][B]
    const int* __restrict__ order,     // [D][N]
    const int* __restrict__ do_idx_p,  // [1]
    const ushort_t* __restrict__ W1A,  // [N][H][KP] fp16
    const ushort_t* __restrict__ mexp, // [D][N][KP]
    const float* __restrict__ W2,      // [N][H]
    const float* __restrict__ b2,      // [N]
    float* __restrict__ out)           // [D][B][N]
{
  const int d = blockIdx.y;
  const int bx = blockIdx.x;
  const int tid = threadIdx.x;
  const int w = tid >> 6;
  const int lane = tid & 63;
  const int g = lane >> 4;      // k-group within wave
  const int n16 = lane & 15;    // row-within-tile
  const int di = __builtin_amdgcn_readfirstlane(do_idx_p[0]);
  const int rowbase = bx * 256 + w * 64 + n16;   // + nt*16 per tile

  // B-operand register file: breg4[nt][S] = 8 fp16 of outs^T
  // lane (g,n16), tile nt, slice S holds k = 32S + 8g + {0..7} for row rowbase+16nt
  uint4 breg4[4][4];
#pragma unroll
  for (int nt = 0; nt < 4; ++nt) {
#pragma unroll
    for (int S = 0; S < 4; ++S) breg4[nt][S] = make_uint4(0u, 0u, 0u, 0u);
    breg4[nt][3].z = 0x3C000000u;  // k=101 ones-row (hi half) for g==0; pad elsewhere
  }

  const int* ord = order + d * NN;
  const ushort_t* mbase_d = mexp + (size_t)d * NN * KP;

#pragma unroll 1
  for (int step = 0; step < NN; ++step) {
    const int node = __builtin_amdgcn_readfirstlane(ord[step]);

    // per-step x column (k=100): load + insert into lo half of [nt][3].z (g==0 owns)
    float xvf[4];
    const float* xp = xT + (size_t)node * BB + rowbase;
#pragma unroll
    for (int nt = 0; nt < 4; ++nt) xvf[nt] = xp[nt * 16];
    {
      const bool own0 = (g == 0);
#pragma unroll
      for (int nt = 0; nt < 4; ++nt) {
        uint old = breg4[nt][3].z;
        uint ins = (old & 0xFFFF0000u) |
                   (uint)__half_as_ushort(__float2half_rn(xvf[nt]));
        breg4[nt][3].z = own0 ? ins : old;
      }
    }

    float val[4];
    if (node != di) {
      const ushort_t* wb = W1A + (size_t)node * HH * KP;
      const ushort_t* mb = mbase_d + (size_t)node * KP;
      const float* w2p = W2 + node * HH;
      float4 w2a4 = *(const float4*)(w2p + 4 * g);        // j = 4g+reg (mt0)
      float4 w2b4 = *(const float4*)(w2p + 16 + 4 * g);   // j = 16+4g+reg (mt1)
      float wa[4] = {w2a4.x, w2a4.y, w2a4.z, w2a4.w};
      float wbv[4] = {w2b4.x, w2b4.y, w2b4.z, w2b4.w};

      f32x4 acc[4][2];
#pragma unroll
      for (int nt = 0; nt < 4; ++nt) {
        acc[nt][0] = (f32x4){0.f, 0.f, 0.f, 0.f};
        acc[nt][1] = (f32x4){0.f, 0.f, 0.f, 0.f};
      }

#pragma unroll
      for (int S = 0; S < 4; ++S) {
        const int koff = 32 * S + 8 * g;
        FU a0, a1, mk;
        a0.u = *(const uint4*)(wb + n16 * KP + koff);          // j = n16
        a1.u = *(const uint4*)(wb + (16 + n16) * KP + koff);   // j = 16+n16
        mk.u = *(const uint4*)(mb + koff);
        a0.u.x &= mk.u.x; a0.u.y &= mk.u.y; a0.u.z &= mk.u.z; a0.u.w &= mk.u.w;
        a1.u.x &= mk.u.x; a1.u.y &= mk.u.y; a1.u.z &= mk.u.z; a1.u.w &= mk.u.w;
#pragma unroll
        for (int nt = 0; nt < 4; ++nt) {
          FU bu; bu.u = breg4[nt][S];
          acc[nt][0] = __builtin_amdgcn_mfma_f32_16x16x32_f16(a0.h, bu.h, acc[nt][0], 0, 0, 0);
          acc[nt][1] = __builtin_amdgcn_mfma_f32_16x16x32_f16(a1.h, bu.h, acc[nt][1], 0, 0, 0);
        }
      }

      const float b2n = b2[node];
#pragma unroll
      for (int nt = 0; nt < 4; ++nt) {
        float p = 0.f;
#pragma unroll
        for (int r4 = 0; r4 < 4; ++r4) {
          float h0 = acc[nt][0][r4]; h0 = fmaxf(h0, 0.01f * h0);
          p = fmaf(wa[r4], h0, p);
          float h1 = acc[nt][1][r4]; h1 = fmaxf(h1, 0.01f * h1);
          p = fmaf(wbv[r4], h1, p);
        }
        p += __shfl_xor(p, 16, 64);   // fold g^1
        p += __shfl_xor(p, 32, 64);   // fold g^2
        val[nt] = p + b2n;
      }
    } else {
#pragma unroll
      for (int nt = 0; nt < 4; ++nt) val[nt] = xvf[nt];
    }

    // insert val (fp16) into breg at k=node: slot S=node>>5, comp=(node>>1)&3,
    // half=node&1, owner lane-group g==(node>>3)&3 — all wave-uniform selects
    const int sn = node >> 5;
    const int en2 = (node >> 1) & 3;
    const int gn = (node >> 3) & 3;
    const int hin = node & 1;
    const bool own = (g == gn);
    ushort_t hv[4];
#pragma unroll
    for (int nt = 0; nt < 4; ++nt) hv[nt] = __half_as_ushort(__float2half_rn(val[nt]));
#pragma unroll
    for (int S = 0; S < 4; ++S) {
      if (S != sn) continue;        // uniform
#pragma unroll
      for (int nt = 0; nt < 4; ++nt) {
        uint4& Bq = breg4[nt][S];
        uint hvn = (uint)hv[nt];
        if (en2 == 0) {
          uint old = Bq.x;
          uint nw = hin ? ((old & 0x0000FFFFu) | (hvn << 16)) : ((old & 0xFFFF0000u) | hvn);
          Bq.x = own ? nw : old;
        } else if (en2 == 1) {
          uint old = Bq.y;
          uint nw = hin ? ((old & 0x0000FFFFu) | (hvn << 16)) : ((old & 0xFFFF0000u) | hvn);
          Bq.y = own ? nw : old;
        } else if (en2 == 2) {
          uint old = Bq.z;
          uint nw = hin ? ((old & 0x0000FFFFu) | (hvn << 16)) : ((old & 0xFFFF0000u) | hvn);
          Bq.z = own ? nw : old;
        } else {
          uint old = Bq.w;
          uint nw = hin ? ((old & 0x0000FFFFu) | (hvn << 16)) : ((old & 0xFFFF0000u) | hvn);
          Bq.w = own ? nw : old;
        }
      }
    }
  }

  // ---- final output: per-wave LDS transpose chunk, then coalesced f32 store
  __shared__ ushort_t tbuf[64 * 132];
  for (int c = 0; c < 4; ++c) {
    __syncthreads();
    if (w == c) {
#pragma unroll
      for (int nt = 0; nt < 4; ++nt) {
        int r = nt * 16 + n16;
#pragma unroll
        for (int S = 0; S < 4; ++S) {
          int k = 32 * S + 8 * g;
          *(uint2*)&tbuf[r * 132 + k] = make_uint2(breg4[nt][S].x, breg4[nt][S].y);
          *(uint2*)&tbuf[r * 132 + k + 4] = make_uint2(breg4[nt][S].z, breg4[nt][S].w);
        }
      }
    }
    __syncthreads();
    const size_t obase = ((size_t)d * BB + bx * 256 + c * 64) * NN;
    for (int idx = tid; idx < 64 * NN; idx += 256) {
      int rl = idx / NN;
      int col = idx - rl * NN;
      out[obase + idx] = __half2float(__ushort_as_half(tbuf[rl * 132 + col]));
    }
  }
}

extern "C" void kernel_launch(void* const* d_in, const int* in_sizes, int n_in,
                              void* d_out, int out_size, void* d_ws, size_t ws_size,
                              hipStream_t stream) {
  const float* x     = (const float*)d_in[0];
  const float* A     = (const float*)d_in[1];
  const int* order   = (const int*)d_in[2];
  const int* do_idx  = (const int*)d_in[3];
  const float* W1    = (const float*)d_in[4];
  const float* b1    = (const float*)d_in[5];
  const float* W2    = (const float*)d_in[6];
  const float* b2    = (const float*)d_in[7];
  float* out = (float*)d_out;

  char* ws = (char*)d_ws;
  float* xT       = (float*)ws;                          // 8192*100*4 = 3,276,800 B
  ushort_t* W1A   = (ushort_t*)(ws + 3276800);           // 100*32*128*2 = 819,200 B
  ushort_t* mexp  = (ushort_t*)(ws + 3276800 + 819200);  // 32*100*128*2 = 819,200 B

  hipLaunchKernelGGL(prep_xt, dim3((BB * NN) / 256), dim3(256), 0, stream, x, xT);
  hipLaunchKernelGGL(prep_w1a, dim3(1600), dim3(256), 0, stream, W1, b1, W1A);
  hipLaunchKernelGGL(prep_mexp, dim3(1600), dim3(256), 0, stream, A, mexp);
  hipLaunchKernelGGL(dag_mfma, dim3(BB / 256, DD), dim3(256), 0, stream,
                     xT, order, do_idx, W1A, mexp, W2, b2, out);
}